// Round 7
// baseline (246.807 us; speedup 1.0000x reference)
//
#include <hip/hip_runtime.h>
#include <math.h>

#define LOG2E 1.4426950408889634f
#define LN2 0.6931471805599453f

constexpr int B_ = 16;
constexpr int T_ = 512;
constexpr int E_ = 512;    // K of GEMM
constexpr int V_ = 5000;   // true N
constexpr int VP_ = 5120;  // padded N (multiple of 128)
constexpr int CB_ = VP_ / 128;   // 40 col-blocks
constexpr int CB2_ = CB_ * 2;    // 80 half-block partials per row
constexpr int L_ = 64;
constexpr int S_ = 2 * L_ + 1;   // 129
constexpr int SP_ = 132;         // padded emit stride (16B-aligned rows)
constexpr int ELW_ = 80;         // EL row width (65 used, padded)

typedef __attribute__((ext_vector_type(8))) short bf16x8;
typedef __attribute__((ext_vector_type(4))) float f32x4;

#define GLOAD_LDS16(g, l)                                                              \
  __builtin_amdgcn_global_load_lds((const __attribute__((address_space(1))) void*)(g), \
                                   (__attribute__((address_space(3))) void*)(l), 16, 0, 0)

__device__ __forceinline__ unsigned short f2bf(float x) {
  unsigned int u = __float_as_uint(x);
  unsigned int r = (u + 0x7fffu + ((u >> 16) & 1u)) >> 16;  // RNE
  return (unsigned short)r;
}
__device__ __forceinline__ float bf2f(unsigned int lo16) {
  return __uint_as_float(lo16 << 16);
}

__device__ __forceinline__ float hexp2(float x) { return __builtin_amdgcn_exp2f(x); }
__device__ __forceinline__ float hlog2(float x) { return __builtin_amdgcn_logf(x); }

// neighbor a1 from lane-1 via DPP: row_shr:1 with row_bcast15 patch; lane0 -> 0
__device__ __forceinline__ float dpp_shr1_zero(float v) {
  int s = __float_as_int(v);
  int bc = __builtin_amdgcn_update_dpp(0, s, 0x142, 0xF, 0xF, false);   // row_bcast15
  int r = __builtin_amdgcn_update_dpp(bc, s, 0x111, 0xF, 0xF, false);   // row_shr:1
  return __int_as_float(r);
}

template <int CTRL>
__device__ __forceinline__ float dpp_mv(float v) {
  int s = __float_as_int(v);
  return __int_as_float(__builtin_amdgcn_update_dpp(s, s, CTRL, 0xF, 0xF, false));
}

// ---------- block reduction helper (256 threads = 4 waves) ----------
__device__ __forceinline__ float blockReduceF(float v, bool is_max, volatile float* red) {
  int tid = threadIdx.x, lane = tid & 63, wid = tid >> 6;
#pragma unroll
  for (int off = 32; off > 0; off >>= 1) {
    float o = __shfl_down(v, off, 64);
    v = is_max ? fmaxf(v, o) : (v + o);
  }
  __syncthreads();
  if (lane == 0) red[wid] = v;
  __syncthreads();
  float r = red[0];
#pragma unroll
  for (int w = 1; w < 4; ++w) r = is_max ? fmaxf(r, (float)red[w]) : (r + (float)red[w]);
  return r;
}

// ---------- conversion: hs_pad f32 -> bf16 ----------
__global__ __launch_bounds__(256) void convA(const float* __restrict__ X,
                                             unsigned short* __restrict__ Y, int n4) {
  int i = blockIdx.x * 256 + threadIdx.x;
  if (i >= n4) return;
  float4 v = ((const float4*)X)[i];
  ushort4 o;
  o.x = f2bf(v.x); o.y = f2bf(v.y); o.z = f2bf(v.z); o.w = f2bf(v.w);
  ((ushort4*)Y)[i] = o;
}

// ---------- conversion: W [512][5000] f32 -> W_T [5120][512] bf16 ----------
__global__ __launch_bounds__(256) void convW(const float* __restrict__ W,
                                             unsigned short* __restrict__ Wt) {
  __shared__ float tile[32][33];
  int n0 = blockIdx.x * 32, k0 = blockIdx.y * 32;
  int tid = threadIdx.x;
  int tx = tid & 31, ty = tid >> 5;
#pragma unroll
  for (int p = 0; p < 4; ++p) {
    int k = k0 + ty + p * 8, n = n0 + tx;
    tile[ty + p * 8][tx] = (n < V_) ? W[(size_t)k * V_ + n] : 0.0f;
  }
  __syncthreads();
#pragma unroll
  for (int p = 0; p < 4; ++p) {
    int n = n0 + ty + p * 8, k = k0 + tx;
    Wt[(size_t)n * E_ + k] = f2bf(tile[tx][ty + p * 8]);
  }
}

// ---------- prep: gather label columns of Wt into Wext[16][80][512] bf16 ----------
__global__ __launch_bounds__(256) void prep_wext(const unsigned short* __restrict__ Wt,
                                                 const int* __restrict__ targets,
                                                 unsigned short* __restrict__ Wext) {
  int b = blockIdx.x;
  int tid = threadIdx.x;
  // 65 slots x 128 ushort4-groups (512 k)
  for (int idx = tid; idx < 65 * 128; idx += 256) {
    int slot = idx >> 7, grp = idx & 127;
    int c = (slot == 0) ? 0 : targets[b * L_ + slot - 1];
    ushort4 v = *(const ushort4*)(Wt + (size_t)c * E_ + grp * 4);
    *(ushort4*)(Wext + ((size_t)b * ELW_ + slot) * E_ + grp * 4) = v;
  }
}

// ---------- Kernel A: fused bf16 MFMA GEMM + per-row KD partials from registers ----------
// No C anywhere. part[row][cb2][3] = (sum e^l, sum e^s, sum e^s * l) over 64-col half-tiles.
__global__ __launch_bounds__(256) void gemm_kd(const unsigned short* __restrict__ A,
                                               const unsigned short* __restrict__ Wt,
                                               const float* __restrict__ bias,
                                               const float* __restrict__ soft,
                                               float* __restrict__ part) {
  __shared__ unsigned short As[128 * 32];
  __shared__ unsigned short Bs[128 * 32];
  int tid = threadIdx.x;
  int l = tid & 63, wid = tid >> 6;
  int lane15 = l & 15, lhalf = l >> 4;
  int wr = wid >> 1, wc = wid & 1;
  int bn = blockIdx.x * 128;
  int bm = blockIdx.y * 128;

  f32x4 acc[4][4] = {};

  int srow = l >> 2;
  int scol = (l & 3) * 8;
  for (int k0 = 0; k0 < E_; k0 += 32) {
#pragma unroll
    for (int i = 0; i < 2; ++i) {
      int rb = wid * 32 + i * 16;
      GLOAD_LDS16(A + (size_t)(bm + rb + srow) * E_ + k0 + scol, &As[rb * 32]);
      GLOAD_LDS16(Wt + (size_t)(bn + rb + srow) * E_ + k0 + scol, &Bs[rb * 32]);
    }
    __syncthreads();
    bf16x8 af[4], bf[4];
#pragma unroll
    for (int m = 0; m < 4; ++m)
      af[m] = *(const bf16x8*)&As[(wr * 64 + m * 16 + lane15) * 32 + lhalf * 8];
#pragma unroll
    for (int n = 0; n < 4; ++n)
      bf[n] = *(const bf16x8*)&Bs[(wc * 64 + n * 16 + lane15) * 32 + lhalf * 8];
#pragma unroll
    for (int m = 0; m < 4; ++m)
#pragma unroll
      for (int n = 0; n < 4; ++n)
        acc[m][n] = __builtin_amdgcn_mfma_f32_16x16x32_bf16(af[m], bf[n], acc[m][n], 0, 0, 0);
    __syncthreads();
  }

  // ---- epilogue: KD partials straight from registers ----
  int colbase = bn + wc * 64 + lane15;  // + n*16
  float bv[4], validf[4];
#pragma unroll
  for (int n = 0; n < 4; ++n) {
    int col = colbase + n * 16;
    bool v = col < V_;
    validf[n] = v ? 1.0f : 0.0f;
    bv[n] = v ? bias[col] : 0.0f;
  }
  int cb2 = blockIdx.x * 2 + wc;
#pragma unroll
  for (int m = 0; m < 4; ++m) {
#pragma unroll
    for (int j = 0; j < 4; ++j) {
      int row = bm + wr * 64 + m * 16 + lhalf * 4 + j;
      const float* sp = soft + (size_t)row * V_ + colbase;
      float pl = 0.f, ps = 0.f, pd = 0.f;
#pragma unroll
      for (int n = 0; n < 4; ++n) {
        float lv = acc[m][n][j] + bv[n];
        float el = hexp2(lv * LOG2E) * validf[n];
        float s = (validf[n] != 0.0f) ? sp[n * 16] : 0.0f;
        float es = hexp2(s * LOG2E) * validf[n];
        pl += el;
        ps += es;
        pd = fmaf(es, lv, pd);
      }
      // reduce across the 16-lane column group
#pragma unroll
      for (int off = 1; off < 16; off <<= 1) {
        pl += __shfl_xor(pl, off, 64);
        ps += __shfl_xor(ps, off, 64);
        pd += __shfl_xor(pd, off, 64);
      }
      if (lane15 == 0) {
        float* pp = part + ((size_t)row * CB2_ + cb2) * 3;
        pp[0] = pl; pp[1] = ps; pp[2] = pd;
      }
    }
  }
}

// ---------- Kernel A2: small GEMM for CTC label logits, EL[8192][80] f32 ----------
__global__ __launch_bounds__(256) void gemm_emit(const unsigned short* __restrict__ A,
                                                 const unsigned short* __restrict__ Wext,
                                                 const float* __restrict__ bias,
                                                 const int* __restrict__ targets,
                                                 float* __restrict__ EL) {
  __shared__ unsigned short As[128 * 32];
  int tid = threadIdx.x;
  int l = tid & 63, wid = tid >> 6;
  int lane15 = l & 15, lhalf = l >> 4;
  int bm = blockIdx.x * 128;
  int bidx = bm >> 9;
  const unsigned short* Wb = Wext + (size_t)bidx * ELW_ * E_;

  f32x4 acc[2][5] = {};
  int srow = l >> 2, scol = (l & 3) * 8;
  for (int k0 = 0; k0 < E_; k0 += 32) {
#pragma unroll
    for (int i = 0; i < 2; ++i) {
      int rb = wid * 32 + i * 16;
      GLOAD_LDS16(A + (size_t)(bm + rb + srow) * E_ + k0 + scol, &As[rb * 32]);
    }
    __syncthreads();
    bf16x8 af[2], bf[5];
#pragma unroll
    for (int m = 0; m < 2; ++m)
      af[m] = *(const bf16x8*)&As[(wid * 32 + m * 16 + lane15) * 32 + lhalf * 8];
#pragma unroll
    for (int n = 0; n < 5; ++n)
      bf[n] = *(const bf16x8*)(Wb + (size_t)(n * 16 + lane15) * E_ + k0 + lhalf * 8);
#pragma unroll
    for (int m = 0; m < 2; ++m)
#pragma unroll
      for (int n = 0; n < 5; ++n)
        acc[m][n] = __builtin_amdgcn_mfma_f32_16x16x32_bf16(af[m], bf[n], acc[m][n], 0, 0, 0);
    __syncthreads();
  }
  // bias per slot (slot 0 = blank col 0; slot s = targets[s-1]); slots >= 65 unused
  float bvE[5];
#pragma unroll
  for (int n = 0; n < 5; ++n) {
    int slot = n * 16 + lane15;
    int c = (slot == 0 || slot >= 65) ? 0 : targets[bidx * L_ + slot - 1];
    bvE[n] = bias[c];
  }
#pragma unroll
  for (int m = 0; m < 2; ++m)
#pragma unroll
    for (int n = 0; n < 5; ++n) {
      int slot = n * 16 + lane15;
#pragma unroll
      for (int j = 0; j < 4; ++j) {
        int row = bm + wid * 32 + m * 16 + lhalf * 4 + j;
        EL[(size_t)row * ELW_ + slot] = acc[m][n][j] + bvE[n];
      }
    }
}

// ---------- Kernel B: finalize rows (sum partials -> lse/cxe; scaled emissions) ----------
__global__ __launch_bounds__(256) void finalize(const float* __restrict__ part,
                                                const float* __restrict__ EL,
                                                const int* __restrict__ hlens,
                                                float* __restrict__ cxe,
                                                float* __restrict__ emit) {
  int row = blockIdx.x * 4 + (threadIdx.x >> 6);
  int l = threadIdx.x & 63;
  int bidx = row >> 9, t = row & (T_ - 1);
  const float* pp = part + (size_t)row * CB2_ * 3;
  float sl = 0.f, ss = 0.f, sd = 0.f;
  for (int idx = l; idx < CB2_; idx += 64) {
    sl += pp[idx * 3]; ss += pp[idx * 3 + 1]; sd += pp[idx * 3 + 2];
  }
#pragma unroll
  for (int off = 32; off > 0; off >>= 1) {
    sl += __shfl_xor(sl, off, 64);
    ss += __shfl_xor(ss, off, 64);
    sd += __shfl_xor(sd, off, 64);
  }
  float lse = hlog2(sl) * LN2;
  if (l == 0) cxe[row] = (t < hlens[bidx]) ? (lse - sd / ss) : 0.0f;

  const float* elr = EL + (size_t)row * ELW_;
  int slot0 = (l & 1) ? (l >> 1) + 1 : 0;
  int slot1 = (l & 1) ? (l >> 1) + 33 : 0;
  float e0 = (elr[slot0] - lse) * LOG2E;
  float e1 = (elr[slot1] - lse) * LOG2E;
  float e2 = (l == 0) ? (elr[0] - lse) * LOG2E : -3e38f;
  float m = fmaxf(fmaxf(e0, e1), e2);
#pragma unroll
  for (int off = 32; off > 0; off >>= 1) m = fmaxf(m, __shfl_xor(m, off, 64));
  float* er = emit + (size_t)row * SP_;
  er[l] = hexp2(e0 - m);
  er[l + 64] = hexp2(e1 - m);
  if (l == 0) {
    er[128] = hexp2(e2 - m);
    er[130] = m;  // K_t
  }
}

// ---------- Kernel C: CTC forward, prob domain, DPP neighbor, renorm every 8 ----------
__device__ __forceinline__ void pstep(float& a0, float& a1, float& a2, float allowf,
                                      float e0, float e1, float e2) {
  float ua1 = dpp_shr1_zero(a1);
  float n0 = (a0 + ua1) * e0;
  float n1 = fmaf(ua1, allowf, a0 + a1) * e1;
  float n2 = (a2 + a1) * e2;
  a0 = n0; a1 = n1; a2 = n2;
}

__device__ __forceinline__ void renorm(float& a0, float& a1, float& a2, float& shift,
                                       int lane) {
  float m = fmaxf(a0, a1);
  m = (lane == 63) ? fmaxf(m, a2) : m;
  m = fmaxf(m, dpp_mv<0xB1>(m));
  m = fmaxf(m, dpp_mv<0x4E>(m));
  m = fmaxf(m, dpp_mv<0x124>(m));
  m = fmaxf(m, dpp_mv<0x128>(m));
  m = fmaxf(m, __shfl_xor(m, 16, 64));
  m = fmaxf(m, __shfl_xor(m, 32, 64));
  m = fmaxf(m, 1e-35f);
  float rs = __builtin_amdgcn_rcpf(m) * 281474976710656.0f;  // *2^48 headroom
  a0 *= rs; a1 *= rs; a2 *= rs;
  shift -= hlog2(rs);
}

__global__ __launch_bounds__(64) void ctc_fwd(const float* __restrict__ emit,
                                              const int* __restrict__ hlens,
                                              const int* __restrict__ targets,
                                              const int* __restrict__ olens,
                                              float* __restrict__ ctc_out) {
  int b = blockIdx.x;
  int l = threadIdx.x;
  const float* Eb = emit + (size_t)b * T_ * SP_;
  float allowf = 0.f;
  if (l >= 1) allowf = (targets[b * L_ + l] != targets[b * L_ + l - 1]) ? 1.0f : 0.0f;

  float a0, a1, a2, shift;
  {
    float2 e01 = *(const float2*)(Eb + 2 * l);
    float4 x = *(const float4*)(Eb + 128);
    a0 = (l == 0) ? e01.x : 0.0f;
    a1 = (l == 0) ? e01.y : 0.0f;
    a2 = 0.0f;
    shift = x.z;  // K_0
  }
  int ilen = hlens[b];

#define LDE(tt) (*(const float2*)(Eb + (size_t)(tt) * SP_ + 2 * l))
#define LDX(tt) (*(const float4*)(Eb + (size_t)(tt) * SP_ + 128))

  float2 c0 = LDE(1), c1 = LDE(2), c2 = LDE(3), c3 = LDE(4);
  float2 c4 = LDE(5), c5 = LDE(6), c6 = LDE(7), c7 = LDE(8);
  float4 x0 = LDX(1), x1 = LDX(2), x2 = LDX(3), x3 = LDX(4);
  float4 x4 = LDX(5), x5 = LDX(6), x6 = LDX(7), x7 = LDX(8);

  int t = 1;
  for (; t + 7 <= ilen - 1; t += 8) {
    float2 p0 = LDE(t + 8), p1 = LDE(t + 9), p2 = LDE(t + 10), p3 = LDE(t + 11);
    float2 p4 = LDE(t + 12), p5 = LDE(t + 13), p6 = LDE(t + 14), p7 = LDE(t + 15);
    float4 q0 = LDX(t + 8), q1 = LDX(t + 9), q2 = LDX(t + 10), q3 = LDX(t + 11);
    float4 q4 = LDX(t + 12), q5 = LDX(t + 13), q6 = LDX(t + 14), q7 = LDX(t + 15);
    pstep(a0, a1, a2, allowf, c0.x, c0.y, x0.x);
    pstep(a0, a1, a2, allowf, c1.x, c1.y, x1.x);
    pstep(a0, a1, a2, allowf, c2.x, c2.y, x2.x);
    pstep(a0, a1, a2, allowf, c3.x, c3.y, x3.x);
    pstep(a0, a1, a2, allowf, c4.x, c4.y, x4.x);
    pstep(a0, a1, a2, allowf, c5.x, c5.y, x5.x);
    pstep(a0, a1, a2, allowf, c6.x, c6.y, x6.x);
    pstep(a0, a1, a2, allowf, c7.x, c7.y, x7.x);
    shift += ((x0.z + x1.z) + (x2.z + x3.z)) + ((x4.z + x5.z) + (x6.z + x7.z));
    renorm(a0, a1, a2, shift, l);
    c0 = p0; c1 = p1; c2 = p2; c3 = p3; c4 = p4; c5 = p5; c6 = p6; c7 = p7;
    x0 = q0; x1 = q1; x2 = q2; x3 = q3; x4 = q4; x5 = q5; x6 = q6; x7 = q7;
  }
  int rem = ilen - t;
  if (rem > 0) { pstep(a0, a1, a2, allowf, c0.x, c0.y, x0.x); shift += x0.z; }
  if (rem > 1) { pstep(a0, a1, a2, allowf, c1.x, c1.y, x1.x); shift += x1.z; }
  if (rem > 2) { pstep(a0, a1, a2, allowf, c2.x, c2.y, x2.x); shift += x2.z; }
  if (rem > 3) { pstep(a0, a1, a2, allowf, c3.x, c3.y, x3.x); shift += x3.z; }
  if (rem > 4) { pstep(a0, a1, a2, allowf, c4.x, c4.y, x4.x); shift += x4.z; }
  if (rem > 5) { pstep(a0, a1, a2, allowf, c5.x, c5.y, x5.x); shift += x5.z; }
  if (rem > 6) { pstep(a0, a1, a2, allowf, c6.x, c6.y, x6.x); shift += x6.z; }
#undef LDE
#undef LDX

  int end = 2 * olens[b];  // 64..128, even
  float aE = (end == 128) ? __shfl(a2, 63, 64) : __shfl(a0, end >> 1, 64);
  float aE1 = __shfl(a1, (end >> 1) - 1, 64);
  if (l == 0) {
    float p = aE + aE1;
    float ll = (hlog2(p) + shift) * LN2;
    float loss = -ll;
    if (!(loss <= 1e20f)) loss = 0.0f;  // zero_infinity (catches inf/nan too)
    ctc_out[b] = loss;
  }
}

// ---------- Kernel D: final combine ----------
__global__ __launch_bounds__(256) void final_reduce(const float* __restrict__ cxe,
                                                    const float* __restrict__ ctco,
                                                    float* __restrict__ out) {
  __shared__ float red[4];
  float s = 0.f;
  for (int i = threadIdx.x; i < B_ * T_; i += 256) s += cxe[i];
  s = blockReduceF(s, false, red);
  if (threadIdx.x == 0) {
    float c = 0.f;
    for (int b = 0; b < B_; ++b) c += ctco[b];
    out[0] = 0.5f * (s / (float)B_) + 0.5f * (c / (float)B_);
  }
}

extern "C" void kernel_launch(void* const* d_in, const int* in_sizes, int n_in,
                              void* d_out, int out_size, void* d_ws, size_t ws_size,
                              hipStream_t stream) {
  const float* hs = (const float*)d_in[0];
  const float* soft = (const float*)d_in[1];
  const float* W = (const float*)d_in[2];
  const float* bias = (const float*)d_in[3];
  const int* hlens = (const int*)d_in[4];
  const int* targets = (const int*)d_in[5];
  const int* olens = (const int*)d_in[6];
  float* out = (float*)d_out;

  int total = B_ * T_;  // 8192 rows
  size_t emit_n = (size_t)(total + 16) * SP_;  // +16 rows slack for ctc prefetch
  float* emit = (float*)d_ws;
  float* cxe = emit + emit_n;
  float* ctco = cxe + (size_t)total;
  unsigned short* Abf = (unsigned short*)(ctco + 16);       // 8192*512 bf16
  unsigned short* Wt = Abf + (size_t)total * E_;            // 5120*512 bf16
  unsigned short* Wext = Wt + (size_t)VP_ * E_;             // 16*80*512 bf16
  float* EL = (float*)(Wext + (size_t)B_ * ELW_ * E_);      // 8192*80 f32
  float* part = EL + (size_t)total * ELW_;                  // 8192*80*3 f32

  dim3 blk(256);
  {
    int n4 = total * E_ / 4;
    hipLaunchKernelGGL(convA, dim3((n4 + 255) / 256), blk, 0, stream, hs, Abf, n4);
    hipLaunchKernelGGL(convW, dim3(VP_ / 32, E_ / 32), blk, 0, stream, W, Wt);
    hipLaunchKernelGGL(prep_wext, dim3(B_), blk, 0, stream, Wt, targets, Wext);
  }

  hipLaunchKernelGGL(gemm_kd, dim3(CB_, total / 128), blk, 0, stream, Abf, Wt, bias,
                     soft, part);
  hipLaunchKernelGGL(gemm_emit, dim3(total / 128), blk, 0, stream, Abf, Wext, bias,
                     targets, EL);
  hipLaunchKernelGGL(finalize, dim3(total / 4), blk, 0, stream, part, EL, hlens, cxe, emit);
  hipLaunchKernelGGL(ctc_fwd, dim3(B_), dim3(64), 0, stream, emit, hlens, targets, olens, ctco);
  hipLaunchKernelGGL(final_reduce, dim3(1), blk, 0, stream, cxe, ctco, out);
}

// Round 8
// 241.693 us; speedup vs baseline: 1.0212x; 1.0212x over previous
//
#include <hip/hip_runtime.h>
#include <math.h>

#define LOG2E 1.4426950408889634f
#define LN2 0.6931471805599453f

constexpr int B_ = 16;
constexpr int T_ = 512;
constexpr int E_ = 512;    // K of GEMM
constexpr int V_ = 5000;   // true N
constexpr int VP_ = 5120;  // padded N (multiple of 128)
constexpr int CB_ = VP_ / 128;   // 40 col-blocks
constexpr int CB2_ = CB_ * 2;    // 80 half-block partials per row
constexpr int L_ = 64;
constexpr int S_ = 2 * L_ + 1;   // 129
constexpr int SP_ = 132;         // padded emit stride (16B-aligned rows)
constexpr int ELW_ = 80;         // EL row width (65 used, padded)

typedef __attribute__((ext_vector_type(8))) short bf16x8;
typedef __attribute__((ext_vector_type(4))) float f32x4;

#define GLOAD_LDS16(g, l)                                                              \
  __builtin_amdgcn_global_load_lds((const __attribute__((address_space(1))) void*)(g), \
                                   (__attribute__((address_space(3))) void*)(l), 16, 0, 0)

__device__ __forceinline__ unsigned short f2bf(float x) {
  unsigned int u = __float_as_uint(x);
  unsigned int r = (u + 0x7fffu + ((u >> 16) & 1u)) >> 16;  // RNE
  return (unsigned short)r;
}
__device__ __forceinline__ float bf2f(unsigned int lo16) {
  return __uint_as_float(lo16 << 16);
}

__device__ __forceinline__ float hexp2(float x) { return __builtin_amdgcn_exp2f(x); }
__device__ __forceinline__ float hlog2(float x) { return __builtin_amdgcn_logf(x); }

// neighbor a1 from lane-1 via DPP: row_shr:1 with row_bcast15 patch; lane0 -> 0
__device__ __forceinline__ float dpp_shr1_zero(float v) {
  int s = __float_as_int(v);
  int bc = __builtin_amdgcn_update_dpp(0, s, 0x142, 0xF, 0xF, false);   // row_bcast15
  int r = __builtin_amdgcn_update_dpp(bc, s, 0x111, 0xF, 0xF, false);   // row_shr:1
  return __int_as_float(r);
}

template <int CTRL>
__device__ __forceinline__ float dpp_mv(float v) {
  int s = __float_as_int(v);
  return __int_as_float(__builtin_amdgcn_update_dpp(s, s, CTRL, 0xF, 0xF, false));
}

// sum across a 16-lane DPP row (pure VALU, no LDS):
// xor1 (quad_perm), xor2 (quad_perm), ror:4, ror:8
__device__ __forceinline__ float dpp_row_sum16(float v) {
  v += dpp_mv<0xB1>(v);
  v += dpp_mv<0x4E>(v);
  v += dpp_mv<0x124>(v);
  v += dpp_mv<0x128>(v);
  return v;
}

// ---------- block reduction helper (256 threads = 4 waves) ----------
__device__ __forceinline__ float blockReduceF(float v, bool is_max, volatile float* red) {
  int tid = threadIdx.x, lane = tid & 63, wid = tid >> 6;
#pragma unroll
  for (int off = 32; off > 0; off >>= 1) {
    float o = __shfl_down(v, off, 64);
    v = is_max ? fmaxf(v, o) : (v + o);
  }
  __syncthreads();
  if (lane == 0) red[wid] = v;
  __syncthreads();
  float r = red[0];
#pragma unroll
  for (int w = 1; w < 4; ++w) r = is_max ? fmaxf(r, (float)red[w]) : (r + (float)red[w]);
  return r;
}

// ---------- conversion: hs_pad f32 -> bf16 ----------
__global__ __launch_bounds__(256) void convA(const float* __restrict__ X,
                                             unsigned short* __restrict__ Y, int n4) {
  int i = blockIdx.x * 256 + threadIdx.x;
  if (i >= n4) return;
  float4 v = ((const float4*)X)[i];
  ushort4 o;
  o.x = f2bf(v.x); o.y = f2bf(v.y); o.z = f2bf(v.z); o.w = f2bf(v.w);
  ((ushort4*)Y)[i] = o;
}

// ---------- conversion: W [512][5000] f32 -> W_T [5120][512] bf16 ----------
__global__ __launch_bounds__(256) void convW(const float* __restrict__ W,
                                             unsigned short* __restrict__ Wt) {
  __shared__ float tile[32][33];
  int n0 = blockIdx.x * 32, k0 = blockIdx.y * 32;
  int tid = threadIdx.x;
  int tx = tid & 31, ty = tid >> 5;
#pragma unroll
  for (int p = 0; p < 4; ++p) {
    int k = k0 + ty + p * 8, n = n0 + tx;
    tile[ty + p * 8][tx] = (n < V_) ? W[(size_t)k * V_ + n] : 0.0f;
  }
  __syncthreads();
#pragma unroll
  for (int p = 0; p < 4; ++p) {
    int n = n0 + ty + p * 8, k = k0 + tx;
    Wt[(size_t)n * E_ + k] = f2bf(tile[tx][ty + p * 8]);
  }
}

// ---------- prep: gather label columns of Wt into Wext[16][80][512] bf16 ----------
__global__ __launch_bounds__(256) void prep_wext(const unsigned short* __restrict__ Wt,
                                                 const int* __restrict__ targets,
                                                 unsigned short* __restrict__ Wext) {
  int b = blockIdx.x;
  int tid = threadIdx.x;
  for (int idx = tid; idx < 65 * 128; idx += 256) {
    int slot = idx >> 7, grp = idx & 127;
    int c = (slot == 0) ? 0 : targets[b * L_ + slot - 1];
    ushort4 v = *(const ushort4*)(Wt + (size_t)c * E_ + grp * 4);
    *(ushort4*)(Wext + ((size_t)b * ELW_ + slot) * E_ + grp * 4) = v;
  }
}

// ---------- Kernel A: fused bf16 MFMA GEMM + per-row KD partials (DPP reduce) ----------
__global__ __launch_bounds__(256) void gemm_kd(const unsigned short* __restrict__ A,
                                               const unsigned short* __restrict__ Wt,
                                               const float* __restrict__ bias,
                                               const float* __restrict__ soft,
                                               float* __restrict__ part) {
  __shared__ unsigned short As[128 * 32];
  __shared__ unsigned short Bs[128 * 32];
  int tid = threadIdx.x;
  int l = tid & 63, wid = tid >> 6;
  int lane15 = l & 15, lhalf = l >> 4;
  int wr = wid >> 1, wc = wid & 1;
  int bn = blockIdx.x * 128;
  int bm = blockIdx.y * 128;

  f32x4 acc[4][4] = {};

  int srow = l >> 2;
  int scol = (l & 3) * 8;
  for (int k0 = 0; k0 < E_; k0 += 32) {
#pragma unroll
    for (int i = 0; i < 2; ++i) {
      int rb = wid * 32 + i * 16;
      GLOAD_LDS16(A + (size_t)(bm + rb + srow) * E_ + k0 + scol, &As[rb * 32]);
      GLOAD_LDS16(Wt + (size_t)(bn + rb + srow) * E_ + k0 + scol, &Bs[rb * 32]);
    }
    __syncthreads();
    bf16x8 af[4], bf[4];
#pragma unroll
    for (int m = 0; m < 4; ++m)
      af[m] = *(const bf16x8*)&As[(wr * 64 + m * 16 + lane15) * 32 + lhalf * 8];
#pragma unroll
    for (int n = 0; n < 4; ++n)
      bf[n] = *(const bf16x8*)&Bs[(wc * 64 + n * 16 + lane15) * 32 + lhalf * 8];
#pragma unroll
    for (int m = 0; m < 4; ++m)
#pragma unroll
      for (int n = 0; n < 4; ++n)
        acc[m][n] = __builtin_amdgcn_mfma_f32_16x16x32_bf16(af[m], bf[n], acc[m][n], 0, 0, 0);
    __syncthreads();
  }

  // ---- epilogue: KD partials straight from registers; 16-lane DPP row reduce ----
  int colbase = bn + wc * 64 + lane15;  // + n*16
  float bv[4], validf[4];
#pragma unroll
  for (int n = 0; n < 4; ++n) {
    int col = colbase + n * 16;
    bool v = col < V_;
    validf[n] = v ? 1.0f : 0.0f;
    bv[n] = v ? bias[col] : 0.0f;
  }
  int cb2 = blockIdx.x * 2 + wc;
#pragma unroll
  for (int m = 0; m < 4; ++m) {
#pragma unroll
    for (int j = 0; j < 4; ++j) {
      int row = bm + wr * 64 + m * 16 + lhalf * 4 + j;
      const float* sp = soft + (size_t)row * V_ + colbase;
      float pl = 0.f, ps = 0.f, pd = 0.f;
#pragma unroll
      for (int n = 0; n < 4; ++n) {
        float lv = acc[m][n][j] + bv[n];
        float el = hexp2(lv * LOG2E) * validf[n];
        float s = (validf[n] != 0.0f) ? sp[n * 16] : 0.0f;
        float es = hexp2(s * LOG2E) * validf[n];
        pl += el;
        ps += es;
        pd = fmaf(es, lv, pd);
      }
      // reduce across the 16-lane column group — pure-VALU DPP, no LDS
      pl = dpp_row_sum16(pl);
      ps = dpp_row_sum16(ps);
      pd = dpp_row_sum16(pd);
      if (lane15 == 0) {
        float* pp = part + ((size_t)row * CB2_ + cb2) * 3;
        pp[0] = pl; pp[1] = ps; pp[2] = pd;
      }
    }
  }
}

// ---------- Kernel A2: small GEMM for CTC label logits, EL[8192][80] f32 ----------
__global__ __launch_bounds__(256) void gemm_emit(const unsigned short* __restrict__ A,
                                                 const unsigned short* __restrict__ Wext,
                                                 const float* __restrict__ bias,
                                                 const int* __restrict__ targets,
                                                 float* __restrict__ EL) {
  __shared__ unsigned short As[128 * 32];
  int tid = threadIdx.x;
  int l = tid & 63, wid = tid >> 6;
  int lane15 = l & 15, lhalf = l >> 4;
  int bm = blockIdx.x * 128;
  int bidx = bm >> 9;
  const unsigned short* Wb = Wext + (size_t)bidx * ELW_ * E_;

  f32x4 acc[2][5] = {};
  int srow = l >> 2, scol = (l & 3) * 8;
  for (int k0 = 0; k0 < E_; k0 += 32) {
#pragma unroll
    for (int i = 0; i < 2; ++i) {
      int rb = wid * 32 + i * 16;
      GLOAD_LDS16(A + (size_t)(bm + rb + srow) * E_ + k0 + scol, &As[rb * 32]);
    }
    __syncthreads();
    bf16x8 af[2], bf[5];
#pragma unroll
    for (int m = 0; m < 2; ++m)
      af[m] = *(const bf16x8*)&As[(wid * 32 + m * 16 + lane15) * 32 + lhalf * 8];
#pragma unroll
    for (int n = 0; n < 5; ++n)
      bf[n] = *(const bf16x8*)(Wb + (size_t)(n * 16 + lane15) * E_ + k0 + lhalf * 8);
#pragma unroll
    for (int m = 0; m < 2; ++m)
#pragma unroll
      for (int n = 0; n < 5; ++n)
        acc[m][n] = __builtin_amdgcn_mfma_f32_16x16x32_bf16(af[m], bf[n], acc[m][n], 0, 0, 0);
    __syncthreads();
  }
  float bvE[5];
#pragma unroll
  for (int n = 0; n < 5; ++n) {
    int slot = n * 16 + lane15;
    int c = (slot == 0 || slot >= 65) ? 0 : targets[bidx * L_ + slot - 1];
    bvE[n] = bias[c];
  }
#pragma unroll
  for (int m = 0; m < 2; ++m)
#pragma unroll
    for (int n = 0; n < 5; ++n) {
      int slot = n * 16 + lane15;
#pragma unroll
      for (int j = 0; j < 4; ++j) {
        int row = bm + wid * 32 + m * 16 + lhalf * 4 + j;
        EL[(size_t)row * ELW_ + slot] = acc[m][n][j] + bvE[n];
      }
    }
}

// ---------- Kernel B: finalize rows (sum partials -> lse/cxe; scaled emissions) ----------
__global__ __launch_bounds__(256) void finalize(const float* __restrict__ part,
                                                const float* __restrict__ EL,
                                                const int* __restrict__ hlens,
                                                float* __restrict__ cxe,
                                                float* __restrict__ emit) {
  int row = blockIdx.x * 4 + (threadIdx.x >> 6);
  int l = threadIdx.x & 63;
  int bidx = row >> 9, t = row & (T_ - 1);
  const float* pp = part + (size_t)row * CB2_ * 3;
  float sl = 0.f, ss = 0.f, sd = 0.f;
  for (int idx = l; idx < CB2_; idx += 64) {
    sl += pp[idx * 3]; ss += pp[idx * 3 + 1]; sd += pp[idx * 3 + 2];
  }
#pragma unroll
  for (int off = 32; off > 0; off >>= 1) {
    sl += __shfl_xor(sl, off, 64);
    ss += __shfl_xor(ss, off, 64);
    sd += __shfl_xor(sd, off, 64);
  }
  float lse = hlog2(sl) * LN2;
  if (l == 0) cxe[row] = (t < hlens[bidx]) ? (lse - sd / ss) : 0.0f;

  const float* elr = EL + (size_t)row * ELW_;
  int slot0 = (l & 1) ? (l >> 1) + 1 : 0;
  int slot1 = (l & 1) ? (l >> 1) + 33 : 0;
  float e0 = (elr[slot0] - lse) * LOG2E;
  float e1 = (elr[slot1] - lse) * LOG2E;
  float e2 = (l == 0) ? (elr[0] - lse) * LOG2E : -3e38f;
  float m = fmaxf(fmaxf(e0, e1), e2);
#pragma unroll
  for (int off = 32; off > 0; off >>= 1) m = fmaxf(m, __shfl_xor(m, off, 64));
  float* er = emit + (size_t)row * SP_;
  er[l] = hexp2(e0 - m);
  er[l + 64] = hexp2(e1 - m);
  if (l == 0) {
    er[128] = hexp2(e2 - m);
    er[130] = m;  // K_t
  }
}

// ---------- Kernel C: CTC forward, prob domain, DPP neighbor, renorm every 8 ----------
__device__ __forceinline__ void pstep(float& a0, float& a1, float& a2, float allowf,
                                      float e0, float e1, float e2) {
  float ua1 = dpp_shr1_zero(a1);
  float n0 = (a0 + ua1) * e0;
  float n1 = fmaf(ua1, allowf, a0 + a1) * e1;
  float n2 = (a2 + a1) * e2;
  a0 = n0; a1 = n1; a2 = n2;
}

__device__ __forceinline__ void renorm(float& a0, float& a1, float& a2, float& shift,
                                       int lane) {
  float m = fmaxf(a0, a1);
  m = (lane == 63) ? fmaxf(m, a2) : m;
  m = fmaxf(m, dpp_mv<0xB1>(m));
  m = fmaxf(m, dpp_mv<0x4E>(m));
  m = fmaxf(m, dpp_mv<0x124>(m));
  m = fmaxf(m, dpp_mv<0x128>(m));
  m = fmaxf(m, __shfl_xor(m, 16, 64));
  m = fmaxf(m, __shfl_xor(m, 32, 64));
  m = fmaxf(m, 1e-35f);
  float rs = __builtin_amdgcn_rcpf(m) * 281474976710656.0f;  // *2^48 headroom
  a0 *= rs; a1 *= rs; a2 *= rs;
  shift -= hlog2(rs);
}

__global__ __launch_bounds__(64) void ctc_fwd(const float* __restrict__ emit,
                                              const int* __restrict__ hlens,
                                              const int* __restrict__ targets,
                                              const int* __restrict__ olens,
                                              float* __restrict__ ctc_out) {
  int b = blockIdx.x;
  int l = threadIdx.x;
  const float* Eb = emit + (size_t)b * T_ * SP_;
  float allowf = 0.f;
  if (l >= 1) allowf = (targets[b * L_ + l] != targets[b * L_ + l - 1]) ? 1.0f : 0.0f;

  float a0, a1, a2, shift;
  {
    float2 e01 = *(const float2*)(Eb + 2 * l);
    float4 x = *(const float4*)(Eb + 128);
    a0 = (l == 0) ? e01.x : 0.0f;
    a1 = (l == 0) ? e01.y : 0.0f;
    a2 = 0.0f;
    shift = x.z;  // K_0
  }
  int ilen = hlens[b];

#define LDE(tt) (*(const float2*)(Eb + (size_t)(tt) * SP_ + 2 * l))
#define LDX(tt) (*(const float4*)(Eb + (size_t)(tt) * SP_ + 128))

  float2 c0 = LDE(1), c1 = LDE(2), c2 = LDE(3), c3 = LDE(4);
  float2 c4 = LDE(5), c5 = LDE(6), c6 = LDE(7), c7 = LDE(8);
  float4 x0 = LDX(1), x1 = LDX(2), x2 = LDX(3), x3 = LDX(4);
  float4 x4 = LDX(5), x5 = LDX(6), x6 = LDX(7), x7 = LDX(8);

  int t = 1;
  for (; t + 7 <= ilen - 1; t += 8) {
    float2 p0 = LDE(t + 8), p1 = LDE(t + 9), p2 = LDE(t + 10), p3 = LDE(t + 11);
    float2 p4 = LDE(t + 12), p5 = LDE(t + 13), p6 = LDE(t + 14), p7 = LDE(t + 15);
    float4 q0 = LDX(t + 8), q1 = LDX(t + 9), q2 = LDX(t + 10), q3 = LDX(t + 11);
    float4 q4 = LDX(t + 12), q5 = LDX(t + 13), q6 = LDX(t + 14), q7 = LDX(t + 15);
    pstep(a0, a1, a2, allowf, c0.x, c0.y, x0.x);
    pstep(a0, a1, a2, allowf, c1.x, c1.y, x1.x);
    pstep(a0, a1, a2, allowf, c2.x, c2.y, x2.x);
    pstep(a0, a1, a2, allowf, c3.x, c3.y, x3.x);
    pstep(a0, a1, a2, allowf, c4.x, c4.y, x4.x);
    pstep(a0, a1, a2, allowf, c5.x, c5.y, x5.x);
    pstep(a0, a1, a2, allowf, c6.x, c6.y, x6.x);
    pstep(a0, a1, a2, allowf, c7.x, c7.y, x7.x);
    shift += ((x0.z + x1.z) + (x2.z + x3.z)) + ((x4.z + x5.z) + (x6.z + x7.z));
    renorm(a0, a1, a2, shift, l);
    c0 = p0; c1 = p1; c2 = p2; c3 = p3; c4 = p4; c5 = p5; c6 = p6; c7 = p7;
    x0 = q0; x1 = q1; x2 = q2; x3 = q3; x4 = q4; x5 = q5; x6 = q6; x7 = q7;
  }
  int rem = ilen - t;
  if (rem > 0) { pstep(a0, a1, a2, allowf, c0.x, c0.y, x0.x); shift += x0.z; }
  if (rem > 1) { pstep(a0, a1, a2, allowf, c1.x, c1.y, x1.x); shift += x1.z; }
  if (rem > 2) { pstep(a0, a1, a2, allowf, c2.x, c2.y, x2.x); shift += x2.z; }
  if (rem > 3) { pstep(a0, a1, a2, allowf, c3.x, c3.y, x3.x); shift += x3.z; }
  if (rem > 4) { pstep(a0, a1, a2, allowf, c4.x, c4.y, x4.x); shift += x4.z; }
  if (rem > 5) { pstep(a0, a1, a2, allowf, c5.x, c5.y, x5.x); shift += x5.z; }
  if (rem > 6) { pstep(a0, a1, a2, allowf, c6.x, c6.y, x6.x); shift += x6.z; }
#undef LDE
#undef LDX

  int end = 2 * olens[b];  // 64..128, even
  float aE = (end == 128) ? __shfl(a2, 63, 64) : __shfl(a0, end >> 1, 64);
  float aE1 = __shfl(a1, (end >> 1) - 1, 64);
  if (l == 0) {
    float p = aE + aE1;
    float ll = (hlog2(p) + shift) * LN2;
    float loss = -ll;
    if (!(loss <= 1e20f)) loss = 0.0f;  // zero_infinity (catches inf/nan too)
    ctc_out[b] = loss;
  }
}

// ---------- Kernel D: final combine ----------
__global__ __launch_bounds__(256) void final_reduce(const float* __restrict__ cxe,
                                                    const float* __restrict__ ctco,
                                                    float* __restrict__ out) {
  __shared__ float red[4];
  float s = 0.f;
  for (int i = threadIdx.x; i < B_ * T_; i += 256) s += cxe[i];
  s = blockReduceF(s, false, red);
  if (threadIdx.x == 0) {
    float c = 0.f;
    for (int b = 0; b < B_; ++b) c += ctco[b];
    out[0] = 0.5f * (s / (float)B_) + 0.5f * (c / (float)B_);
  }
}

extern "C" void kernel_launch(void* const* d_in, const int* in_sizes, int n_in,
                              void* d_out, int out_size, void* d_ws, size_t ws_size,
                              hipStream_t stream) {
  const float* hs = (const float*)d_in[0];
  const float* soft = (const float*)d_in[1];
  const float* W = (const float*)d_in[2];
  const float* bias = (const float*)d_in[3];
  const int* hlens = (const int*)d_in[4];
  const int* targets = (const int*)d_in[5];
  const int* olens = (const int*)d_in[6];
  float* out = (float*)d_out;

  int total = B_ * T_;  // 8192 rows
  size_t emit_n = (size_t)(total + 16) * SP_;  // +16 rows slack for ctc prefetch
  float* emit = (float*)d_ws;
  float* cxe = emit + emit_n;
  float* ctco = cxe + (size_t)total;
  unsigned short* Abf = (unsigned short*)(ctco + 16);       // 8192*512 bf16
  unsigned short* Wt = Abf + (size_t)total * E_;            // 5120*512 bf16
  unsigned short* Wext = Wt + (size_t)VP_ * E_;             // 16*80*512 bf16
  float* EL = (float*)(Wext + (size_t)B_ * ELW_ * E_);      // 8192*80 f32
  float* part = EL + (size_t)total * ELW_;                  // 8192*80*3 f32

  dim3 blk(256);
  {
    int n4 = total * E_ / 4;
    hipLaunchKernelGGL(convA, dim3((n4 + 255) / 256), blk, 0, stream, hs, Abf, n4);
    hipLaunchKernelGGL(convW, dim3(VP_ / 32, E_ / 32), blk, 0, stream, W, Wt);
    hipLaunchKernelGGL(prep_wext, dim3(B_), blk, 0, stream, Wt, targets, Wext);
  }

  hipLaunchKernelGGL(gemm_kd, dim3(CB_, total / 128), blk, 0, stream, Abf, Wt, bias,
                     soft, part);
  hipLaunchKernelGGL(gemm_emit, dim3(total / 128), blk, 0, stream, Abf, Wext, bias,
                     targets, EL);
  hipLaunchKernelGGL(finalize, dim3(total / 4), blk, 0, stream, part, EL, hlens, cxe, emit);
  hipLaunchKernelGGL(ctc_fwd, dim3(B_), dim3(64), 0, stream, emit, hlens, targets, olens, ctco);
  hipLaunchKernelGGL(final_reduce, dim3(1), blk, 0, stream, cxe, ctco, out);
}

// Round 9
// 178.546 us; speedup vs baseline: 1.3823x; 1.3537x over previous
//
#include <hip/hip_runtime.h>
#include <math.h>

#define LOG2E 1.4426950408889634f
#define LN2 0.6931471805599453f

constexpr int B_ = 16;
constexpr int T_ = 512;
constexpr int E_ = 512;    // K of GEMM
constexpr int V_ = 5000;   // true N
constexpr int VP_ = 5120;  // padded N (multiple of 128)
constexpr int L_ = 64;
constexpr int S_ = 2 * L_ + 1;  // 129
constexpr int SP_ = 132;        // padded emit stride (16B-aligned rows)

typedef __attribute__((ext_vector_type(8))) short bf16x8;
typedef __attribute__((ext_vector_type(4))) float f32x4;

#define GLOAD_LDS16(g, l)                                                              \
  __builtin_amdgcn_global_load_lds((const __attribute__((address_space(1))) void*)(g), \
                                   (__attribute__((address_space(3))) void*)(l), 16, 0, 0)

__device__ __forceinline__ unsigned short f2bf(float x) {
  unsigned int u = __float_as_uint(x);
  unsigned int r = (u + 0x7fffu + ((u >> 16) & 1u)) >> 16;  // RNE
  return (unsigned short)r;
}
__device__ __forceinline__ float bf2f(unsigned int lo16) {
  return __uint_as_float(lo16 << 16);
}

__device__ __forceinline__ float hexp2(float x) { return __builtin_amdgcn_exp2f(x); }
__device__ __forceinline__ float hlog2(float x) { return __builtin_amdgcn_logf(x); }

// neighbor a1 from lane-1 via DPP: row_shr:1 with row_bcast15 patch; lane0 -> 0
__device__ __forceinline__ float dpp_shr1_zero(float v) {
  int s = __float_as_int(v);
  int bc = __builtin_amdgcn_update_dpp(0, s, 0x142, 0xF, 0xF, false);   // row_bcast15
  int r = __builtin_amdgcn_update_dpp(bc, s, 0x111, 0xF, 0xF, false);   // row_shr:1
  return __int_as_float(r);
}

template <int CTRL>
__device__ __forceinline__ float dpp_mv(float v) {
  int s = __float_as_int(v);
  return __int_as_float(__builtin_amdgcn_update_dpp(s, s, CTRL, 0xF, 0xF, false));
}

// ---------- block reduction helper (256 threads = 4 waves of 64) ----------
__device__ __forceinline__ float blockReduceF(float v, bool is_max, volatile float* red) {
  int tid = threadIdx.x, lane = tid & 63, wid = tid >> 6;
#pragma unroll
  for (int off = 32; off > 0; off >>= 1) {
    float o = __shfl_down(v, off, 64);
    v = is_max ? fmaxf(v, o) : (v + o);
  }
  __syncthreads();
  if (lane == 0) red[wid] = v;
  __syncthreads();
  float r = red[0];
#pragma unroll
  for (int w = 1; w < 4; ++w) r = is_max ? fmaxf(r, (float)red[w]) : (r + (float)red[w]);
  return r;
}

// ---------- conversion: hs_pad f32 -> bf16 ----------
__global__ __launch_bounds__(256) void convA(const float* __restrict__ X,
                                             unsigned short* __restrict__ Y, int n4) {
  int i = blockIdx.x * 256 + threadIdx.x;
  if (i >= n4) return;
  float4 v = ((const float4*)X)[i];
  ushort4 o;
  o.x = f2bf(v.x); o.y = f2bf(v.y); o.z = f2bf(v.z); o.w = f2bf(v.w);
  ((ushort4*)Y)[i] = o;
}

// ---------- conversion: W [512][5000] f32 -> W_T [5120][512] bf16 ----------
__global__ __launch_bounds__(256) void convW(const float* __restrict__ W,
                                             unsigned short* __restrict__ Wt) {
  __shared__ float tile[32][33];
  int n0 = blockIdx.x * 32, k0 = blockIdx.y * 32;
  int tid = threadIdx.x;
  int tx = tid & 31, ty = tid >> 5;
#pragma unroll
  for (int p = 0; p < 4; ++p) {
    int k = k0 + ty + p * 8, n = n0 + tx;
    tile[ty + p * 8][tx] = (n < V_) ? W[(size_t)k * V_ + n] : 0.0f;
  }
  __syncthreads();
#pragma unroll
  for (int p = 0; p < 4; ++p) {
    int n = n0 + ty + p * 8, k = k0 + tx;
    Wt[(size_t)n * E_ + k] = f2bf(tile[tx][ty + p * 8]);
  }
}

// ---------- Kernel A: bf16 MFMA GEMM, XOR-swizzled LDS, C out in bf16 ----------
// LDS slot (row, chunk16B) holds global chunk (chunk ^ ((row>>1)&3)).
// Staging: linear LDS dest (global_load_lds), inverse-swizzled GLOBAL source.
// Read: same XOR applied to the chunk index. Both reduce to per-lane constants.
__global__ __launch_bounds__(256) void gemm_mfma(const unsigned short* __restrict__ A,
                                                 const unsigned short* __restrict__ Wt,
                                                 const float* __restrict__ bias,
                                                 unsigned short* __restrict__ C) {
  __shared__ unsigned short As[128 * 32];
  __shared__ unsigned short Bs[128 * 32];
  int tid = threadIdx.x;
  int l = tid & 63, wid = tid >> 6;
  int lane15 = l & 15, lhalf = l >> 4;
  int wr = wid >> 1, wc = wid & 1;
  int bm = blockIdx.y * 128;
  int bn = blockIdx.x * 128;

  f32x4 acc[4][4] = {};

  int srow = l >> 2;                               // 0..15 row within 16-row group
  int scol = (((l & 3) ^ ((l >> 3) & 3)) << 3);    // swizzled source chunk * 8 shorts
  int rswz = ((lhalf ^ ((lane15 >> 1) & 3)) << 3); // swizzled read chunk * 8 shorts
  for (int k0 = 0; k0 < E_; k0 += 32) {
#pragma unroll
    for (int i = 0; i < 2; ++i) {
      int rb = wid * 32 + i * 16;
      GLOAD_LDS16(A + (size_t)(bm + rb + srow) * E_ + k0 + scol, &As[rb * 32]);
      GLOAD_LDS16(Wt + (size_t)(bn + rb + srow) * E_ + k0 + scol, &Bs[rb * 32]);
    }
    __syncthreads();
    bf16x8 af[4], bf[4];
#pragma unroll
    for (int m = 0; m < 4; ++m)
      af[m] = *(const bf16x8*)&As[(wr * 64 + m * 16 + lane15) * 32 + rswz];
#pragma unroll
    for (int n = 0; n < 4; ++n)
      bf[n] = *(const bf16x8*)&Bs[(wc * 64 + n * 16 + lane15) * 32 + rswz];
#pragma unroll
    for (int m = 0; m < 4; ++m)
#pragma unroll
      for (int n = 0; n < 4; ++n)
        acc[m][n] = __builtin_amdgcn_mfma_f32_16x16x32_bf16(af[m], bf[n], acc[m][n], 0, 0, 0);
    __syncthreads();
  }

#pragma unroll
  for (int n = 0; n < 4; ++n) {
    int col = bn + wc * 64 + n * 16 + lane15;
    float bv = (col < V_) ? bias[col] : 0.0f;
#pragma unroll
    for (int m = 0; m < 4; ++m) {
      int row0 = bm + wr * 64 + m * 16 + lhalf * 4;
#pragma unroll
      for (int j = 0; j < 4; ++j) {
        C[(size_t)(row0 + j) * VP_ + col] = f2bf(acc[m][n][j] + bv);
      }
    }
  }
}

// ---------- Kernel B: per-row stats fully in registers (no big LDS) ----------
__global__ __launch_bounds__(256) void row_fused(const unsigned short* __restrict__ Cc,
                                                 const float* __restrict__ soft,
                                                 const int* __restrict__ hlens,
                                                 const int* __restrict__ targets,
                                                 float* __restrict__ cxe,
                                                 float* __restrict__ emit, int r0) {
  int r = blockIdx.x;
  int row = r0 + r;
  int bidx = row >> 9;
  int t = row & (T_ - 1);
  const unsigned short* crow = Cc + (size_t)r * VP_;
  const uint4* lrow = (const uint4*)crow;
  const float4* srow = (const float4*)(soft + (size_t)row * V_);
  __shared__ float red[4];
  int tid = threadIdx.x;

  uint4 lu[3];
  float4 sv[3][2];
  bool valid[3];
#pragma unroll
  for (int k = 0; k < 3; ++k) {
    int slot = tid + k * 256;
    valid[k] = (slot < V_ / 8);  // 625
    if (valid[k]) {
      lu[k] = lrow[slot];
      sv[k][0] = srow[slot * 2];
      sv[k][1] = srow[slot * 2 + 1];
    }
  }

  // pass 1: maxima from registers
  float maxl = -INFINITY, maxs = -INFINITY;
#pragma unroll
  for (int k = 0; k < 3; ++k) {
    if (valid[k]) {
      unsigned int w0 = lu[k].x, w1 = lu[k].y, w2 = lu[k].z, w3 = lu[k].w;
      maxl = fmaxf(maxl, fmaxf(fmaxf(bf2f(w0 & 0xffffu), bf2f(w0 >> 16)),
                               fmaxf(bf2f(w1 & 0xffffu), bf2f(w1 >> 16))));
      maxl = fmaxf(maxl, fmaxf(fmaxf(bf2f(w2 & 0xffffu), bf2f(w2 >> 16)),
                               fmaxf(bf2f(w3 & 0xffffu), bf2f(w3 >> 16))));
      float4 a = sv[k][0], b = sv[k][1];
      maxs = fmaxf(maxs, fmaxf(fmaxf(a.x, a.y), fmaxf(a.z, a.w)));
      maxs = fmaxf(maxs, fmaxf(fmaxf(b.x, b.y), fmaxf(b.z, b.w)));
    }
  }
  maxl = blockReduceF(maxl, true, red);
  maxs = blockReduceF(maxs, true, red);

  // pass 2: sums from registers
  float suml = 0.f, sums = 0.f, dot = 0.f;
#pragma unroll
  for (int k = 0; k < 3; ++k) {
    if (valid[k]) {
      float lv[8], ss[8];
      unsigned int w0 = lu[k].x, w1 = lu[k].y, w2 = lu[k].z, w3 = lu[k].w;
      lv[0] = bf2f(w0 & 0xffffu); lv[1] = bf2f(w0 >> 16);
      lv[2] = bf2f(w1 & 0xffffu); lv[3] = bf2f(w1 >> 16);
      lv[4] = bf2f(w2 & 0xffffu); lv[5] = bf2f(w2 >> 16);
      lv[6] = bf2f(w3 & 0xffffu); lv[7] = bf2f(w3 >> 16);
      float4 a = sv[k][0], b = sv[k][1];
      ss[0] = a.x; ss[1] = a.y; ss[2] = a.z; ss[3] = a.w;
      ss[4] = b.x; ss[5] = b.y; ss[6] = b.z; ss[7] = b.w;
#pragma unroll
      for (int j = 0; j < 8; ++j) {
        suml += hexp2((lv[j] - maxl) * LOG2E);
        float e = hexp2((ss[j] - maxs) * LOG2E);
        sums += e;
        dot = fmaf(e, lv[j], dot);
      }
    }
  }
  suml = blockReduceF(suml, false, red);
  sums = blockReduceF(sums, false, red);
  dot = blockReduceF(dot, false, red);

  float lse = maxl + hlog2(suml) * LN2;
  if (tid == 0) {
    cxe[row] = (t < hlens[bidx]) ? (lse - dot / sums) : 0.0f;
  }

  // wave 0: emission gather (129 label logits) + wave max + scaled store
  if (tid < 64) {
    int i0 = tid, i1 = tid + 64;
    int idx0 = (i0 & 1) ? targets[bidx * L_ + (i0 >> 1)] : 0;
    int idx1 = (i1 & 1) ? targets[bidx * L_ + (i1 >> 1)] : 0;
    float e0 = (bf2f(crow[idx0]) - lse) * LOG2E;
    float e1 = (bf2f(crow[idx1]) - lse) * LOG2E;
    float e2 = 0.f;
    if (tid == 0) e2 = (bf2f(crow[0]) - lse) * LOG2E;  // s=128 blank
    float m = fmaxf(e0, e1);
    if (tid == 0) m = fmaxf(m, e2);
#pragma unroll
    for (int off = 32; off > 0; off >>= 1) m = fmaxf(m, __shfl_xor(m, off, 64));
    float* erow = emit + ((size_t)bidx * T_ + t) * SP_;
    erow[i0] = hexp2(e0 - m);
    erow[i1] = hexp2(e1 - m);
    if (tid == 0) {
      erow[128] = hexp2(e2 - m);
      erow[130] = m;  // K_t
    }
  }
}

// ---------- Kernel C: CTC forward, prob domain, DPP neighbor, renorm every 8 ----------
__device__ __forceinline__ void pstep(float& a0, float& a1, float& a2, float allowf,
                                      float e0, float e1, float e2) {
  float ua1 = dpp_shr1_zero(a1);
  float n0 = (a0 + ua1) * e0;
  float n1 = fmaf(ua1, allowf, a0 + a1) * e1;
  float n2 = (a2 + a1) * e2;
  a0 = n0; a1 = n1; a2 = n2;
}

__device__ __forceinline__ void renorm(float& a0, float& a1, float& a2, float& shift,
                                       int lane) {
  float m = fmaxf(a0, a1);
  m = (lane == 63) ? fmaxf(m, a2) : m;
  m = fmaxf(m, dpp_mv<0xB1>(m));
  m = fmaxf(m, dpp_mv<0x4E>(m));
  m = fmaxf(m, dpp_mv<0x124>(m));
  m = fmaxf(m, dpp_mv<0x128>(m));
  m = fmaxf(m, __shfl_xor(m, 16, 64));
  m = fmaxf(m, __shfl_xor(m, 32, 64));
  m = fmaxf(m, 1e-35f);
  float rs = __builtin_amdgcn_rcpf(m) * 281474976710656.0f;  // *2^48 headroom
  a0 *= rs; a1 *= rs; a2 *= rs;
  shift -= hlog2(rs);
}

__global__ __launch_bounds__(64) void ctc_fwd(const float* __restrict__ emit,
                                              const int* __restrict__ hlens,
                                              const int* __restrict__ targets,
                                              const int* __restrict__ olens,
                                              float* __restrict__ ctc_out) {
  int b = blockIdx.x;
  int l = threadIdx.x;
  const float* Eb = emit + (size_t)b * T_ * SP_;
  float allowf = 0.f;
  if (l >= 1) allowf = (targets[b * L_ + l] != targets[b * L_ + l - 1]) ? 1.0f : 0.0f;

  float a0, a1, a2, shift;
  {
    float2 e01 = *(const float2*)(Eb + 2 * l);
    float4 x = *(const float4*)(Eb + 128);
    a0 = (l == 0) ? e01.x : 0.0f;
    a1 = (l == 0) ? e01.y : 0.0f;
    a2 = 0.0f;
    shift = x.z;  // K_0
  }
  int ilen = hlens[b];

#define LDE(tt) (*(const float2*)(Eb + (size_t)(tt) * SP_ + 2 * l))
#define LDX(tt) (*(const float4*)(Eb + (size_t)(tt) * SP_ + 128))

  float2 c0 = LDE(1), c1 = LDE(2), c2 = LDE(3), c3 = LDE(4);
  float2 c4 = LDE(5), c5 = LDE(6), c6 = LDE(7), c7 = LDE(8);
  float4 x0 = LDX(1), x1 = LDX(2), x2 = LDX(3), x3 = LDX(4);
  float4 x4 = LDX(5), x5 = LDX(6), x6 = LDX(7), x7 = LDX(8);

  int t = 1;
  for (; t + 7 <= ilen - 1; t += 8) {
    float2 p0 = LDE(t + 8), p1 = LDE(t + 9), p2 = LDE(t + 10), p3 = LDE(t + 11);
    float2 p4 = LDE(t + 12), p5 = LDE(t + 13), p6 = LDE(t + 14), p7 = LDE(t + 15);
    float4 q0 = LDX(t + 8), q1 = LDX(t + 9), q2 = LDX(t + 10), q3 = LDX(t + 11);
    float4 q4 = LDX(t + 12), q5 = LDX(t + 13), q6 = LDX(t + 14), q7 = LDX(t + 15);
    pstep(a0, a1, a2, allowf, c0.x, c0.y, x0.x);
    pstep(a0, a1, a2, allowf, c1.x, c1.y, x1.x);
    pstep(a0, a1, a2, allowf, c2.x, c2.y, x2.x);
    pstep(a0, a1, a2, allowf, c3.x, c3.y, x3.x);
    pstep(a0, a1, a2, allowf, c4.x, c4.y, x4.x);
    pstep(a0, a1, a2, allowf, c5.x, c5.y, x5.x);
    pstep(a0, a1, a2, allowf, c6.x, c6.y, x6.x);
    pstep(a0, a1, a2, allowf, c7.x, c7.y, x7.x);
    shift += ((x0.z + x1.z) + (x2.z + x3.z)) + ((x4.z + x5.z) + (x6.z + x7.z));
    renorm(a0, a1, a2, shift, l);
    c0 = p0; c1 = p1; c2 = p2; c3 = p3; c4 = p4; c5 = p5; c6 = p6; c7 = p7;
    x0 = q0; x1 = q1; x2 = q2; x3 = q3; x4 = q4; x5 = q5; x6 = q6; x7 = q7;
  }
  int rem = ilen - t;
  if (rem > 0) { pstep(a0, a1, a2, allowf, c0.x, c0.y, x0.x); shift += x0.z; }
  if (rem > 1) { pstep(a0, a1, a2, allowf, c1.x, c1.y, x1.x); shift += x1.z; }
  if (rem > 2) { pstep(a0, a1, a2, allowf, c2.x, c2.y, x2.x); shift += x2.z; }
  if (rem > 3) { pstep(a0, a1, a2, allowf, c3.x, c3.y, x3.x); shift += x3.z; }
  if (rem > 4) { pstep(a0, a1, a2, allowf, c4.x, c4.y, x4.x); shift += x4.z; }
  if (rem > 5) { pstep(a0, a1, a2, allowf, c5.x, c5.y, x5.x); shift += x5.z; }
  if (rem > 6) { pstep(a0, a1, a2, allowf, c6.x, c6.y, x6.x); shift += x6.z; }
#undef LDE
#undef LDX

  int end = 2 * olens[b];  // 64..128, even
  float aE = (end == 128) ? __shfl(a2, 63, 64) : __shfl(a0, end >> 1, 64);
  float aE1 = __shfl(a1, (end >> 1) - 1, 64);
  if (l == 0) {
    float p = aE + aE1;
    float ll = (hlog2(p) + shift) * LN2;
    float loss = -ll;
    if (!(loss <= 1e20f)) loss = 0.0f;  // zero_infinity (catches inf/nan too)
    ctc_out[b] = loss;
  }
}

// ---------- Kernel D: final combine ----------
__global__ __launch_bounds__(256) void final_reduce(const float* __restrict__ cxe,
                                                    const float* __restrict__ ctco,
                                                    float* __restrict__ out) {
  __shared__ float red[4];
  float s = 0.f;
  for (int i = threadIdx.x; i < B_ * T_; i += 256) s += cxe[i];
  s = blockReduceF(s, false, red);
  if (threadIdx.x == 0) {
    float c = 0.f;
    for (int b = 0; b < B_; ++b) c += ctco[b];
    out[0] = 0.5f * (s / (float)B_) + 0.5f * (c / (float)B_);
  }
}

extern "C" void kernel_launch(void* const* d_in, const int* in_sizes, int n_in,
                              void* d_out, int out_size, void* d_ws, size_t ws_size,
                              hipStream_t stream) {
  const float* hs = (const float*)d_in[0];
  const float* soft = (const float*)d_in[1];
  const float* W = (const float*)d_in[2];
  const float* bias = (const float*)d_in[3];
  const int* hlens = (const int*)d_in[4];
  const int* targets = (const int*)d_in[5];
  const int* olens = (const int*)d_in[6];
  float* out = (float*)d_out;

  int total = B_ * T_;
  size_t emit_n = (size_t)(total + 16) * SP_;
  float* emit = (float*)d_ws;
  float* cxe = emit + emit_n;
  float* ctco = cxe + (size_t)total;
  unsigned short* Abf = (unsigned short*)(ctco + 16);
  unsigned short* Wt = Abf + (size_t)total * E_;
  unsigned short* logits = Wt + (size_t)VP_ * E_;  // bf16 chunk buffer
  size_t used = (size_t)((char*)logits - (char*)d_ws);
  size_t avail = (ws_size > used) ? (ws_size - used) : 0;
  int max_rows = (int)(avail / ((size_t)VP_ * sizeof(unsigned short)));
  int chunk = max_rows & ~127;
  if (chunk > total) chunk = total;
  if (chunk < 128) chunk = 128;

  dim3 blk(256);
  {
    int n4 = total * E_ / 4;
    hipLaunchKernelGGL(convA, dim3((n4 + 255) / 256), blk, 0, stream, hs, Abf, n4);
    hipLaunchKernelGGL(convW, dim3(VP_ / 32, E_ / 32), blk, 0, stream, W, Wt);
  }

  for (int r0 = 0; r0 < total; r0 += chunk) {
    int mc = total - r0;
    if (mc > chunk) mc = chunk;
    dim3 g1(VP_ / 128, mc / 128);
    hipLaunchKernelGGL(gemm_mfma, g1, blk, 0, stream, Abf + (size_t)r0 * E_, Wt, bias, logits);
    hipLaunchKernelGGL(row_fused, dim3(mc), blk, 0, stream, logits, soft, hlens, targets,
                       cxe, emit, r0);
  }
  hipLaunchKernelGGL(ctc_fwd, dim3(B_), dim3(64), 0, stream, emit, hlens, targets, olens, ctco);
  hipLaunchKernelGGL(final_reduce, dim3(1), blk, 0, stream, cxe, ctco, out);
}